// Round 1
// baseline (92.934 us; speedup 1.0000x reference)
//
#include <hip/hip_runtime.h>

// Problem constants (match reference)
#define NB 32768
#define ND 512
#define NK 10
static __device__ __forceinline__ float sq(float v) { return v * v; }

#define LEFTB (-10.0f)
#define RIGHTB (10.0f)

// ---------------------------------------------------------------------------
// Kernel 1: per-feature spline tables.
// edges : [ND][12]      internal knots cw[1..9] (padded row of 12 for alignment)
// params: [ND][NK][8]   {cw_k, w_k, ch_k, h_k, delta_k, d_k, d_{k+1}, 0}
// ---------------------------------------------------------------------------
__global__ void rqs_precompute(const float* __restrict__ uw,
                               const float* __restrict__ uh,
                               const float* __restrict__ ud,
                               float* __restrict__ edges,
                               float* __restrict__ params) {
    int f = blockIdx.x * blockDim.x + threadIdx.x;
    if (f >= ND) return;

    float cw[NK + 1], ch[NK + 1], w[NK], h[NK], dd[NK + 1];

    // ---- widths: softmax -> min-width mix -> cumsum knots -> re-diff ----
    {
        float u[NK];
        float m = -1e30f;
#pragma unroll
        for (int k = 0; k < NK; ++k) { u[k] = uw[f * NK + k]; m = fmaxf(m, u[k]); }
        float s = 0.0f;
#pragma unroll
        for (int k = 0; k < NK; ++k) { u[k] = expf(u[k] - m); s += u[k]; }
        float inv = 1.0f / s;
        float c = 0.0f;
        cw[0] = LEFTB;
#pragma unroll
        for (int k = 0; k < NK; ++k) {
            float wk = 1e-3f + (1.0f - 1e-3f * NK) * (u[k] * inv);
            c += wk;
            cw[k + 1] = (RIGHTB - LEFTB) * c + LEFTB;
        }
        cw[NK] = RIGHTB;
#pragma unroll
        for (int k = 0; k < NK; ++k) w[k] = cw[k + 1] - cw[k];
    }
    // ---- heights ----
    {
        float u[NK];
        float m = -1e30f;
#pragma unroll
        for (int k = 0; k < NK; ++k) { u[k] = uh[f * NK + k]; m = fmaxf(m, u[k]); }
        float s = 0.0f;
#pragma unroll
        for (int k = 0; k < NK; ++k) { u[k] = expf(u[k] - m); s += u[k]; }
        float inv = 1.0f / s;
        float c = 0.0f;
        ch[0] = LEFTB;
#pragma unroll
        for (int k = 0; k < NK; ++k) {
            float hk = 1e-3f + (1.0f - 1e-3f * NK) * (u[k] * inv);
            c += hk;
            ch[k + 1] = (RIGHTB - LEFTB) * c + LEFTB;
        }
        ch[NK] = RIGHTB;
#pragma unroll
        for (int k = 0; k < NK; ++k) h[k] = ch[k + 1] - ch[k];
    }
    // ---- derivatives: boundary pads give exactly 1.0 ----
    dd[0] = 1.0f;
    dd[NK] = 1.0f;
#pragma unroll
    for (int k = 1; k < NK; ++k) {
        float v = ud[f * (NK - 1) + (k - 1)];
        // softplus(v) = max(v,0) + log1p(exp(-|v|))
        dd[k] = 1e-3f + (fmaxf(v, 0.0f) + log1pf(expf(-fabsf(v))));
    }

    // ---- store ----
#pragma unroll
    for (int k = 1; k < NK; ++k) edges[f * 12 + (k - 1)] = cw[k];
    edges[f * 12 + 9] = 0.0f; edges[f * 12 + 10] = 0.0f; edges[f * 12 + 11] = 0.0f;
#pragma unroll
    for (int k = 0; k < NK; ++k) {
        float* p = params + ((size_t)(f * NK + k)) * 8;
        p[0] = cw[k];
        p[1] = w[k];
        p[2] = ch[k];
        p[3] = h[k];
        p[4] = h[k] / w[k];   // delta
        p[5] = dd[k];
        p[6] = dd[k + 1];
        p[7] = 0.0f;
    }
}

// ---------------------------------------------------------------------------
// Kernel 2: main transform. One thread per feature (block = 512 = all of D),
// grid-stride over rows. Bin-search edges live in registers; per-bin params
// are a 32 B L1-resident gather. Per-row logdet reduced via shuffles + LDS.
// ---------------------------------------------------------------------------
__global__ __launch_bounds__(512) void rqs_main(const float* __restrict__ X,
                                                const float* __restrict__ edges,
                                                const float* __restrict__ params,
                                                float* __restrict__ Y,
                                                float* __restrict__ logdet) {
    const int t = threadIdx.x;  // feature index
    __shared__ float sred[8];

    float e[9];
#pragma unroll
    for (int j = 0; j < 9; ++j) e[j] = edges[t * 12 + j];

    const float4* P = (const float4*)params;

    for (int r = blockIdx.x; r < NB; r += gridDim.x) {
        const size_t base = (size_t)r * ND + t;
        float x = X[base];
        bool inside = (x >= LEFTB) && (x <= RIGHTB);
        float xc = fminf(fmaxf(x, LEFTB), RIGHTB);

        int idx = 0;
#pragma unroll
        for (int j = 0; j < 9; ++j) idx += (xc >= e[j]) ? 1 : 0;

        const float4 a = P[(t * NK + idx) * 2];      // {cw, w, ch, h}
        const float4 b = P[(t * NK + idx) * 2 + 1];  // {delta, dk, dk1, 0}

        float theta = (xc - a.x) / a.y;
        float omt = 1.0f - theta;
        float t1m = theta * omt;
        float th2 = theta * theta;

        float num = a.w * (b.x * th2 + b.y * t1m);
        float den = b.x + (b.y + b.z - 2.0f * b.x) * t1m;
        float y = a.z + num / den;

        float dnum = b.x * b.x * (b.z * th2 + 2.0f * b.x * t1m + b.y * omt * omt);
        float lad = __logf(dnum) - 2.0f * __logf(den);

        y = inside ? y : x;
        lad = inside ? lad : 0.0f;

        Y[base] = y;

        // ---- per-row reduction of lad across 512 threads ----
        float v = lad;
#pragma unroll
        for (int off = 32; off >= 1; off >>= 1) v += __shfl_xor(v, off, 64);
        if ((t & 63) == 0) sred[t >> 6] = v;
        __syncthreads();
        if (t < 64) {
            float s = (t < 8) ? sred[t] : 0.0f;
#pragma unroll
            for (int off = 4; off >= 1; off >>= 1) s += __shfl_xor(s, off, 64);
            if (t == 0) logdet[r] = s;
        }
        __syncthreads();
    }
}

extern "C" void kernel_launch(void* const* d_in, const int* in_sizes, int n_in,
                              void* d_out, int out_size, void* d_ws, size_t ws_size,
                              hipStream_t stream) {
    const float* x  = (const float*)d_in[0];
    const float* uw = (const float*)d_in[1];
    const float* uh = (const float*)d_in[2];
    const float* ud = (const float*)d_in[3];

    float* out = (float*)d_out;
    float* Y = out;                              // [NB*ND]
    float* logdet = out + (size_t)NB * ND;       // [NB]

    float* edges = (float*)d_ws;                 // ND*12 floats  (24 KB)
    float* params = edges + ND * 12;             // ND*NK*8 floats (160 KB)

    hipLaunchKernelGGL(rqs_precompute, dim3(2), dim3(256), 0, stream,
                       uw, uh, ud, edges, params);
    hipLaunchKernelGGL(rqs_main, dim3(2048), dim3(512), 0, stream,
                       x, edges, params, Y, logdet);
}